// Round 10
// baseline (91.336 us; speedup 1.0000x reference)
//
#include <hip/hip_runtime.h>

typedef float f4v __attribute__((ext_vector_type(4)));    // MFMA accumulator

#define GAS __attribute__((address_space(1)))
#define LAS __attribute__((address_space(3)))

constexpr float INV_COS = 1.0f / 128.0f;

// ---- fp32 -> fp8 e4m3 (OCP), packed 4/dword via v_cvt_pk_fp8_f32 ----
__global__ __launch_bounds__(256) void k_convert(const float* __restrict__ X,
                                                 unsigned* __restrict__ X8) {
    int idx = blockIdx.x * 256 + threadIdx.x;        // one dword = 4 fp8
    float4 v = *(const float4*)(X + (size_t)idx * 4);
    int p = __builtin_amdgcn_cvt_pk_fp8_f32(v.x, v.y, 0, false);   // bytes 0,1
    p     = __builtin_amdgcn_cvt_pk_fp8_f32(v.z, v.w, p, true);    // bytes 2,3
    X8[idx] = (unsigned)p;
}

// ---- symmetric 128x128-tile gemm + exp + row/col sums, fp8 staging (R9-verified) ----
// Monolithic staging, ONE vmcnt(0) drain, 64 MFMA per barrier, 32 KiB LDS.
// Epilogue reductions now use MULTI-VALUE butterflies: 16 row-sums across 16
// lanes in 15 shuffles (vs 64), value r lands on lane mrow==r; 4 col-sums
// across q in 3 shuffles (vs 8), value q lands on lane q; one store per lane.
// partial[row][128] slot map (R3/R5-verified): row r in tile-row b gets
// row-sum slots [2b,128), col-sum slots [0,2b). Exact cover, no atomics.
__global__ __launch_bounds__(256) void k_gemm_rowsum(const unsigned char* __restrict__ X8,
                                                     float* __restrict__ partial) {
    __shared__ __align__(16) unsigned char ldsA[128 * 128];   // 16 KiB
    __shared__ __align__(16) unsigned char ldsB[128 * 128];   // 16 KiB

    // linear block id -> upper-triangular (by, bx), 64x64 tile grid
    int rem = blockIdx.x;
    int by = 0;
    while (rem >= 64 - by) { rem -= 64 - by; ++by; }
    const int bx = by + rem;
    const bool offdiag = (bx != by);

    const int tid  = threadIdx.x;
    const int wave = tid >> 6;
    const int lane = tid & 63;
    const int rA = by * 128;
    const int rB = bx * 128;

    // ---- staging: each wave loads 4 groups of 8 rows (1 KiB each) per matrix ----
    {
        const int lr8 = lane >> 3;     // row within 8-row group
        const int cph = lane & 7;      // physical 16B-chunk slot
#pragma unroll
        for (int t = 0; t < 4; ++t) {
            int g = wave * 4 + t;                  // 16 groups of 8 rows
            int r_loc = g * 8 + lr8;
            int c_log = cph ^ (r_loc & 7);
            const unsigned char* ga = X8 + (size_t)(rA + r_loc) * 128 + c_log * 16;
            const unsigned char* gb = X8 + (size_t)(rB + r_loc) * 128 + c_log * 16;
            __builtin_amdgcn_global_load_lds((const GAS void*)ga, (LAS void*)&ldsA[g * 1024], 16, 0, 0);
            __builtin_amdgcn_global_load_lds((const GAS void*)gb, (LAS void*)&ldsB[g * 1024], 16, 0, 0);
        }
    }
    __syncthreads();

    const int q    = lane >> 4;    // quad 0..3
    const int mrow = lane & 15;
    const int wm   = wave >> 1;    // 2x2 wave grid over 128x128 tile
    const int wn   = wave & 1;

    f4v acc[4][4];
#pragma unroll
    for (int a = 0; a < 4; ++a)
#pragma unroll
        for (int b = 0; b < 4; ++b)
            acc[a][b] = (f4v){0.f, 0.f, 0.f, 0.f};

#pragma unroll
    for (int ks = 0; ks < 4; ++ks) {               // K-steps of 32
        long af[4], bfr[4];
        const int cp   = (ks * 2 + (q >> 1)) ^ (mrow & 7);
        const int boff = (q & 1) * 8;
#pragma unroll
        for (int mi = 0; mi < 4; ++mi) {
            int ra = wm * 64 + mi * 16 + mrow;     // ra&7 == mrow&7 (bases %8==0)
            int rb = wn * 64 + mi * 16 + mrow;
            af[mi]  = *(const long*)&ldsA[ra * 128 + cp * 16 + boff];
            bfr[mi] = *(const long*)&ldsB[rb * 128 + cp * 16 + boff];
        }
#pragma unroll
        for (int mi = 0; mi < 4; ++mi)
#pragma unroll
            for (int ni = 0; ni < 4; ++ni)
                acc[mi][ni] = __builtin_amdgcn_mfma_f32_16x16x32_fp8_fp8(af[mi], bfr[ni], acc[mi][ni], 0, 0, 0);
    }

    // ---- epilogue: e = exp(1 + g/128); lane holds
    // G[wm*64+mi*16+q*4+t][wn*64+ni*16+mrow]
    float v[16];            // row partials, index r = mi*4+t
    float c4[4] = {0.f, 0.f, 0.f, 0.f};
#pragma unroll
    for (int r = 0; r < 16; ++r) v[r] = 0.f;

#pragma unroll
    for (int mi = 0; mi < 4; ++mi)
#pragma unroll
        for (int ni = 0; ni < 4; ++ni)
#pragma unroll
            for (int t = 0; t < 4; ++t) {
                float e = __expf(fmaf(acc[mi][ni][t], INV_COS, 1.0f));
                v[mi * 4 + t] += e;
                c4[ni]        += e;
            }

    // row-sums: multi-value butterfly across mrow; value r ends on lane mrow==r
    float r8[8], r4[4], r2[2], r1;
    {
        const int b = (mrow >> 3) & 1;
#pragma unroll
        for (int k = 0; k < 8; ++k)
            r8[k] = v[b * 8 + k] + __shfl_xor(v[(1 - b) * 8 + k], 8);
    }
    {
        const int b = (mrow >> 2) & 1;
#pragma unroll
        for (int k = 0; k < 4; ++k)
            r4[k] = r8[b * 4 + k] + __shfl_xor(r8[(1 - b) * 4 + k], 4);
    }
    {
        const int b = (mrow >> 1) & 1;
#pragma unroll
        for (int k = 0; k < 2; ++k)
            r2[k] = r4[b * 2 + k] + __shfl_xor(r4[(1 - b) * 2 + k], 2);
    }
    {
        const int b = mrow & 1;
        r1 = r2[b] + __shfl_xor(r2[1 - b], 1);
    }
    {
        int row_loc = wm * 64 + (mrow >> 2) * 16 + q * 4 + (mrow & 3);
        partial[(size_t)(rA + row_loc) * 128 + (bx * 2 + wn)] = r1;
    }

    if (offdiag) {
        // col-sums: butterfly across q (xor32 -> index bit1, xor16 -> bit0);
        // value ni ends on lanes with q==ni
        float c2[2], c1;
        {
            const int b = (q >> 1) & 1;
#pragma unroll
            for (int k = 0; k < 2; ++k)
                c2[k] = c4[b * 2 + k] + __shfl_xor(c4[(1 - b) * 2 + k], 32);
        }
        {
            const int b = q & 1;
            c1 = c2[b] + __shfl_xor(c2[1 - b], 16);
        }
        int col_loc = wn * 64 + q * 16 + mrow;
        partial[(size_t)(rB + col_loc) * 128 + (by * 2 + wm)] = c1;
    }
}

// ---- finalize 1: one wave per pair, deterministic per-block sums ----
__global__ __launch_bounds__(256) void k_finalize1(const float* __restrict__ X,
                                                   const float* __restrict__ partial,
                                                   float* __restrict__ blocksum) {
    __shared__ float ls[4];
    int wave = threadIdx.x >> 6, lane = threadIdx.x & 63;
    int p = blockIdx.x * 4 + wave;
    int i = 2 * p, j = i + 1;

    float pi = partial[(size_t)i * 128 + lane] + partial[(size_t)i * 128 + 64 + lane];
    float pj = partial[(size_t)j * 128 + lane] + partial[(size_t)j * 128 + 64 + lane];
    float xi0 = X[(size_t)i * 128 + lane], xi1 = X[(size_t)i * 128 + 64 + lane];
    float xj0 = X[(size_t)j * 128 + lane], xj1 = X[(size_t)j * 128 + 64 + lane];
    float dii = xi0 * xi0 + xi1 * xi1;
    float dij = xi0 * xj0 + xi1 * xj1;
    float djj = xj0 * xj0 + xj1 * xj1;

#pragma unroll
    for (int m = 1; m < 64; m <<= 1) {
        pi  += __shfl_xor(pi, m);
        pj  += __shfl_xor(pj, m);
        dii += __shfl_xor(dii, m);
        dij += __shfl_xor(dij, m);
        djj += __shfl_xor(djj, m);
    }
    if (lane == 0) {
        dii *= INV_COS; dij *= INV_COS; djj *= INV_COS;
        float eii = __expf(1.0f + dii);
        float eij = __expf(1.0f + dij);
        float ejj = __expf(1.0f + djj);
        float dissim = (pi - eii - eij) + (pj - eij - ejj);
        float J = __logf(1e-8f + dissim) - dij;
        ls[wave] = (J > 0.f) ? J * J : 0.f;
    }
    __syncthreads();
    if (threadIdx.x == 0)
        blocksum[blockIdx.x] = ls[0] + ls[1] + ls[2] + ls[3];
}

// ---- finalize 2: single block reduces 1024 block sums ----
__global__ __launch_bounds__(256) void k_finalize2(const float* __restrict__ blocksum,
                                                   float* __restrict__ out) {
    __shared__ float ls[4];
    int t = threadIdx.x;
    float s = blocksum[t] + blocksum[t + 256] + blocksum[t + 512] + blocksum[t + 768];
#pragma unroll
    for (int m = 1; m < 64; m <<= 1) s += __shfl_xor(s, m);
    if ((t & 63) == 0) ls[t >> 6] = s;
    __syncthreads();
    if (t == 0) out[0] = (ls[0] + ls[1] + ls[2] + ls[3]) * (1.0f / 16384.0f);
}

extern "C" void kernel_launch(void* const* d_in, const int* in_sizes, int n_in,
                              void* d_out, int out_size, void* d_ws, size_t ws_size,
                              hipStream_t stream) {
    const float* X = (const float*)d_in[0];
    char* ws = (char*)d_ws;
    unsigned* X8 = (unsigned*)ws;                        // 1 MiB fp8 input
    float* partial  = (float*)(ws + (1u << 20));         // 4 MiB: partial[8192][128]
    float* blocksum = (float*)(ws + (5u << 20));         // 4 KiB
    float* out      = (float*)d_out;

    hipLaunchKernelGGL(k_convert,     dim3(1024), dim3(256), 0, stream, X, X8);
    hipLaunchKernelGGL(k_gemm_rowsum, dim3(2080), dim3(256), 0, stream, (const unsigned char*)X8, partial);
    hipLaunchKernelGGL(k_finalize1,   dim3(1024), dim3(256), 0, stream, X, partial, blocksum);
    hipLaunchKernelGGL(k_finalize2,   dim3(1),    dim3(256), 0, stream, blocksum, out);
}

// Round 11
// 77.501 us; speedup vs baseline: 1.1785x; 1.1785x over previous
//
#include <hip/hip_runtime.h>

typedef float f4v __attribute__((ext_vector_type(4)));    // MFMA accumulator

#define GAS __attribute__((address_space(1)))
#define LAS __attribute__((address_space(3)))

constexpr float INV_COS = 1.0f / 128.0f;

// ---- fp32 -> fp8 e4m3 (OCP), packed 4/dword via v_cvt_pk_fp8_f32 ----
__global__ __launch_bounds__(256) void k_convert(const float* __restrict__ X,
                                                 unsigned* __restrict__ X8) {
    int idx = blockIdx.x * 256 + threadIdx.x;        // one dword = 4 fp8
    float4 v = *(const float4*)(X + (size_t)idx * 4);
    int p = __builtin_amdgcn_cvt_pk_fp8_f32(v.x, v.y, 0, false);   // bytes 0,1
    p     = __builtin_amdgcn_cvt_pk_fp8_f32(v.z, v.w, p, true);    // bytes 2,3
    X8[idx] = (unsigned)p;
}

// ---- symmetric 128x128-tile gemm + exp + row/col sums, fp8 staging (R9-verified) ----
// Monolithic staging, ONE vmcnt(0) drain, 64 MFMA per barrier, 32 KiB LDS.
// Epilogue: multi-value butterfly with STATIC register indexing (R10's algebra
// — correctness-proven — but own/send picked via per-lane cndmask, never
// runtime array subscripts). 15 shuffles for 16 row-sums, 3 for 4 col-sums.
// partial[row][128] slot map (R3/R5-verified): row r in tile-row b gets
// row-sum slots [2b,128), col-sum slots [0,2b). Exact cover, no atomics.
__global__ __launch_bounds__(256) void k_gemm_rowsum(const unsigned char* __restrict__ X8,
                                                     float* __restrict__ partial) {
    __shared__ __align__(16) unsigned char ldsA[128 * 128];   // 16 KiB
    __shared__ __align__(16) unsigned char ldsB[128 * 128];   // 16 KiB

    // linear block id -> upper-triangular (by, bx), 64x64 tile grid
    int rem = blockIdx.x;
    int by = 0;
    while (rem >= 64 - by) { rem -= 64 - by; ++by; }
    const int bx = by + rem;
    const bool offdiag = (bx != by);

    const int tid  = threadIdx.x;
    const int wave = tid >> 6;
    const int lane = tid & 63;
    const int rA = by * 128;
    const int rB = bx * 128;

    // ---- staging: each wave loads 4 groups of 8 rows (1 KiB each) per matrix ----
    {
        const int lr8 = lane >> 3;     // row within 8-row group
        const int cph = lane & 7;      // physical 16B-chunk slot
#pragma unroll
        for (int t = 0; t < 4; ++t) {
            int g = wave * 4 + t;                  // 16 groups of 8 rows
            int r_loc = g * 8 + lr8;
            int c_log = cph ^ (r_loc & 7);
            const unsigned char* ga = X8 + (size_t)(rA + r_loc) * 128 + c_log * 16;
            const unsigned char* gb = X8 + (size_t)(rB + r_loc) * 128 + c_log * 16;
            __builtin_amdgcn_global_load_lds((const GAS void*)ga, (LAS void*)&ldsA[g * 1024], 16, 0, 0);
            __builtin_amdgcn_global_load_lds((const GAS void*)gb, (LAS void*)&ldsB[g * 1024], 16, 0, 0);
        }
    }
    __syncthreads();

    const int q    = lane >> 4;    // quad 0..3
    const int mrow = lane & 15;
    const int wm   = wave >> 1;    // 2x2 wave grid over 128x128 tile
    const int wn   = wave & 1;

    f4v acc[4][4];
#pragma unroll
    for (int a = 0; a < 4; ++a)
#pragma unroll
        for (int b = 0; b < 4; ++b)
            acc[a][b] = (f4v){0.f, 0.f, 0.f, 0.f};

#pragma unroll
    for (int ks = 0; ks < 4; ++ks) {               // K-steps of 32
        long af[4], bfr[4];
        const int cp   = (ks * 2 + (q >> 1)) ^ (mrow & 7);
        const int boff = (q & 1) * 8;
#pragma unroll
        for (int mi = 0; mi < 4; ++mi) {
            int ra = wm * 64 + mi * 16 + mrow;     // ra&7 == mrow&7 (bases %8==0)
            int rb = wn * 64 + mi * 16 + mrow;
            af[mi]  = *(const long*)&ldsA[ra * 128 + cp * 16 + boff];
            bfr[mi] = *(const long*)&ldsB[rb * 128 + cp * 16 + boff];
        }
#pragma unroll
        for (int mi = 0; mi < 4; ++mi)
#pragma unroll
            for (int ni = 0; ni < 4; ++ni)
                acc[mi][ni] = __builtin_amdgcn_mfma_f32_16x16x32_fp8_fp8(af[mi], bfr[ni], acc[mi][ni], 0, 0, 0);
    }

    // ---- epilogue: e = exp(1 + g/128); lane holds
    // G[wm*64+mi*16+q*4+t][wn*64+ni*16+mrow]
    float v[16];            // row partials, index r = mi*4+t (compile-time only)
    float c4[4] = {0.f, 0.f, 0.f, 0.f};
#pragma unroll
    for (int r = 0; r < 16; ++r) v[r] = 0.f;

#pragma unroll
    for (int mi = 0; mi < 4; ++mi)
#pragma unroll
        for (int ni = 0; ni < 4; ++ni)
#pragma unroll
            for (int t = 0; t < 4; ++t) {
                float e = __expf(fmaf(acc[mi][ni][t], INV_COS, 1.0f));
                v[mi * 4 + t] += e;
                c4[ni]        += e;
            }

    // row-sums: multi-value butterfly across mrow, STATIC indices + cndmask.
    // After all stages value r sits on lane mrow==r (R10-verified algebra).
    float r1;
    {
        const bool b8 = (mrow & 8) != 0;
        float r8[8];
#pragma unroll
        for (int k = 0; k < 8; ++k) {
            float own  = b8 ? v[8 + k] : v[k];
            float send = b8 ? v[k]     : v[8 + k];
            r8[k] = own + __shfl_xor(send, 8);
        }
        const bool b4 = (mrow & 4) != 0;
        float r4[4];
#pragma unroll
        for (int k = 0; k < 4; ++k) {
            float own  = b4 ? r8[4 + k] : r8[k];
            float send = b4 ? r8[k]     : r8[4 + k];
            r4[k] = own + __shfl_xor(send, 4);
        }
        const bool b2 = (mrow & 2) != 0;
        float r2[2];
#pragma unroll
        for (int k = 0; k < 2; ++k) {
            float own  = b2 ? r4[2 + k] : r4[k];
            float send = b2 ? r4[k]     : r4[2 + k];
            r2[k] = own + __shfl_xor(send, 2);
        }
        const bool b1 = (mrow & 1) != 0;
        {
            float own  = b1 ? r2[1] : r2[0];
            float send = b1 ? r2[0] : r2[1];
            r1 = own + __shfl_xor(send, 1);
        }
    }
    {
        int row_loc = wm * 64 + (mrow >> 2) * 16 + q * 4 + (mrow & 3);
        partial[(size_t)(rA + row_loc) * 128 + (bx * 2 + wn)] = r1;
    }

    if (offdiag) {
        // col-sums: butterfly across q (xor32 -> bit1, xor16 -> bit0);
        // value ni lands on lanes with q==ni (R10-verified algebra).
        const bool cb1 = (q & 2) != 0;
        float c2[2];
#pragma unroll
        for (int k = 0; k < 2; ++k) {
            float own  = cb1 ? c4[2 + k] : c4[k];
            float send = cb1 ? c4[k]     : c4[2 + k];
            c2[k] = own + __shfl_xor(send, 32);
        }
        const bool cb0 = (q & 1) != 0;
        float c1;
        {
            float own  = cb0 ? c2[1] : c2[0];
            float send = cb0 ? c2[0] : c2[1];
            c1 = own + __shfl_xor(send, 16);
        }
        int col_loc = wn * 64 + q * 16 + mrow;
        partial[(size_t)(rB + col_loc) * 128 + (by * 2 + wm)] = c1;
    }
}

// ---- finalize 1: one wave per pair, deterministic per-block sums ----
__global__ __launch_bounds__(256) void k_finalize1(const float* __restrict__ X,
                                                   const float* __restrict__ partial,
                                                   float* __restrict__ blocksum) {
    __shared__ float ls[4];
    int wave = threadIdx.x >> 6, lane = threadIdx.x & 63;
    int p = blockIdx.x * 4 + wave;
    int i = 2 * p, j = i + 1;

    float pi = partial[(size_t)i * 128 + lane] + partial[(size_t)i * 128 + 64 + lane];
    float pj = partial[(size_t)j * 128 + lane] + partial[(size_t)j * 128 + 64 + lane];
    float xi0 = X[(size_t)i * 128 + lane], xi1 = X[(size_t)i * 128 + 64 + lane];
    float xj0 = X[(size_t)j * 128 + lane], xj1 = X[(size_t)j * 128 + 64 + lane];
    float dii = xi0 * xi0 + xi1 * xi1;
    float dij = xi0 * xj0 + xi1 * xj1;
    float djj = xj0 * xj0 + xj1 * xj1;

#pragma unroll
    for (int m = 1; m < 64; m <<= 1) {
        pi  += __shfl_xor(pi, m);
        pj  += __shfl_xor(pj, m);
        dii += __shfl_xor(dii, m);
        dij += __shfl_xor(dij, m);
        djj += __shfl_xor(djj, m);
    }
    if (lane == 0) {
        dii *= INV_COS; dij *= INV_COS; djj *= INV_COS;
        float eii = __expf(1.0f + dii);
        float eij = __expf(1.0f + dij);
        float ejj = __expf(1.0f + djj);
        float dissim = (pi - eii - eij) + (pj - eij - ejj);
        float J = __logf(1e-8f + dissim) - dij;
        ls[wave] = (J > 0.f) ? J * J : 0.f;
    }
    __syncthreads();
    if (threadIdx.x == 0)
        blocksum[blockIdx.x] = ls[0] + ls[1] + ls[2] + ls[3];
}

// ---- finalize 2: single block reduces 1024 block sums ----
__global__ __launch_bounds__(256) void k_finalize2(const float* __restrict__ blocksum,
                                                   float* __restrict__ out) {
    __shared__ float ls[4];
    int t = threadIdx.x;
    float s = blocksum[t] + blocksum[t + 256] + blocksum[t + 512] + blocksum[t + 768];
#pragma unroll
    for (int m = 1; m < 64; m <<= 1) s += __shfl_xor(s, m);
    if ((t & 63) == 0) ls[t >> 6] = s;
    __syncthreads();
    if (t == 0) out[0] = (ls[0] + ls[1] + ls[2] + ls[3]) * (1.0f / 16384.0f);
}

extern "C" void kernel_launch(void* const* d_in, const int* in_sizes, int n_in,
                              void* d_out, int out_size, void* d_ws, size_t ws_size,
                              hipStream_t stream) {
    const float* X = (const float*)d_in[0];
    char* ws = (char*)d_ws;
    unsigned* X8 = (unsigned*)ws;                        // 1 MiB fp8 input
    float* partial  = (float*)(ws + (1u << 20));         // 4 MiB: partial[8192][128]
    float* blocksum = (float*)(ws + (5u << 20));         // 4 KiB
    float* out      = (float*)d_out;

    hipLaunchKernelGGL(k_convert,     dim3(1024), dim3(256), 0, stream, X, X8);
    hipLaunchKernelGGL(k_gemm_rowsum, dim3(2080), dim3(256), 0, stream, (const unsigned char*)X8, partial);
    hipLaunchKernelGGL(k_finalize1,   dim3(1024), dim3(256), 0, stream, X, partial, blocksum);
    hipLaunchKernelGGL(k_finalize2,   dim3(1),    dim3(256), 0, stream, blocksum, out);
}

// Round 12
// 76.933 us; speedup vs baseline: 1.1872x; 1.0074x over previous
//
#include <hip/hip_runtime.h>

typedef float f4v __attribute__((ext_vector_type(4)));    // MFMA accumulator

#define GAS __attribute__((address_space(1)))
#define LAS __attribute__((address_space(3)))

constexpr float INV_COS = 1.0f / 128.0f;
constexpr float LOG2E   = 1.4426950408889634f;
constexpr float EXP_C1  = LOG2E / 128.0f;   // exp(1 + g/128) = exp2(g*C1 + C2)
constexpr float EXP_C2  = LOG2E;

#if __has_builtin(__builtin_amdgcn_exp2f)
#define EXP2(x) __builtin_amdgcn_exp2f(x)      // raw v_exp_f32, no OCML wrapper
#else
#define EXP2(x) exp2f(x)
#endif

// ---- fp32 -> fp8 e4m3 (OCP), packed 4/dword via v_cvt_pk_fp8_f32 ----
__global__ __launch_bounds__(256) void k_convert(const float* __restrict__ X,
                                                 unsigned* __restrict__ X8) {
    int idx = blockIdx.x * 256 + threadIdx.x;        // one dword = 4 fp8
    float4 v = *(const float4*)(X + (size_t)idx * 4);
    int p = __builtin_amdgcn_cvt_pk_fp8_f32(v.x, v.y, 0, false);   // bytes 0,1
    p     = __builtin_amdgcn_cvt_pk_fp8_f32(v.z, v.w, p, true);    // bytes 2,3
    X8[idx] = (unsigned)p;
}

// ---- symmetric 128x128-tile gemm + exp + row/col sums, fp8 staging (R9/R11-verified) ----
// Monolithic staging, ONE vmcnt(0) drain, 64 MFMA per barrier, 32 KiB LDS.
// Epilogue: v_exp_f32 via builtin (prefused exp2 constants — saves the mul),
// static-index multi-value butterfly (R11-verified: 15 shuffles row, 3 col).
// partial[row][128] slot map (R3/R5-verified): row r in tile-row b gets
// row-sum slots [2b,128), col-sum slots [0,2b). Exact cover, no atomics.
__global__ __launch_bounds__(256) void k_gemm_rowsum(const unsigned char* __restrict__ X8,
                                                     float* __restrict__ partial) {
    __shared__ __align__(16) unsigned char ldsA[128 * 128];   // 16 KiB
    __shared__ __align__(16) unsigned char ldsB[128 * 128];   // 16 KiB

    // linear block id -> upper-triangular (by, bx), 64x64 tile grid
    int rem = blockIdx.x;
    int by = 0;
    while (rem >= 64 - by) { rem -= 64 - by; ++by; }
    const int bx = by + rem;
    const bool offdiag = (bx != by);

    const int tid  = threadIdx.x;
    const int wave = tid >> 6;
    const int lane = tid & 63;
    const int rA = by * 128;
    const int rB = bx * 128;

    // ---- staging: each wave loads 4 groups of 8 rows (1 KiB each) per matrix ----
    {
        const int lr8 = lane >> 3;     // row within 8-row group
        const int cph = lane & 7;      // physical 16B-chunk slot
#pragma unroll
        for (int t = 0; t < 4; ++t) {
            int g = wave * 4 + t;                  // 16 groups of 8 rows
            int r_loc = g * 8 + lr8;
            int c_log = cph ^ (r_loc & 7);
            const unsigned char* ga = X8 + (size_t)(rA + r_loc) * 128 + c_log * 16;
            const unsigned char* gb = X8 + (size_t)(rB + r_loc) * 128 + c_log * 16;
            __builtin_amdgcn_global_load_lds((const GAS void*)ga, (LAS void*)&ldsA[g * 1024], 16, 0, 0);
            __builtin_amdgcn_global_load_lds((const GAS void*)gb, (LAS void*)&ldsB[g * 1024], 16, 0, 0);
        }
    }
    __syncthreads();

    const int q    = lane >> 4;    // quad 0..3
    const int mrow = lane & 15;
    const int wm   = wave >> 1;    // 2x2 wave grid over 128x128 tile
    const int wn   = wave & 1;

    f4v acc[4][4];
#pragma unroll
    for (int a = 0; a < 4; ++a)
#pragma unroll
        for (int b = 0; b < 4; ++b)
            acc[a][b] = (f4v){0.f, 0.f, 0.f, 0.f};

#pragma unroll
    for (int ks = 0; ks < 4; ++ks) {               // K-steps of 32
        long af[4], bfr[4];
        const int cp   = (ks * 2 + (q >> 1)) ^ (mrow & 7);
        const int boff = (q & 1) * 8;
#pragma unroll
        for (int mi = 0; mi < 4; ++mi) {
            int ra = wm * 64 + mi * 16 + mrow;     // ra&7 == mrow&7 (bases %8==0)
            int rb = wn * 64 + mi * 16 + mrow;
            af[mi]  = *(const long*)&ldsA[ra * 128 + cp * 16 + boff];
            bfr[mi] = *(const long*)&ldsB[rb * 128 + cp * 16 + boff];
        }
#pragma unroll
        for (int mi = 0; mi < 4; ++mi)
#pragma unroll
            for (int ni = 0; ni < 4; ++ni)
                acc[mi][ni] = __builtin_amdgcn_mfma_f32_16x16x32_fp8_fp8(af[mi], bfr[ni], acc[mi][ni], 0, 0, 0);
    }

    // ---- epilogue: e = exp2(g*C1 + C2) = exp(1 + g/128); lane holds
    // G[wm*64+mi*16+q*4+t][wn*64+ni*16+mrow]
    float v[16];            // row partials, index r = mi*4+t (compile-time only)
    float c4[4] = {0.f, 0.f, 0.f, 0.f};
#pragma unroll
    for (int r = 0; r < 16; ++r) v[r] = 0.f;

#pragma unroll
    for (int mi = 0; mi < 4; ++mi)
#pragma unroll
        for (int ni = 0; ni < 4; ++ni) {
            float e0 = EXP2(fmaf(acc[mi][ni][0], EXP_C1, EXP_C2));
            float e1 = EXP2(fmaf(acc[mi][ni][1], EXP_C1, EXP_C2));
            float e2 = EXP2(fmaf(acc[mi][ni][2], EXP_C1, EXP_C2));
            float e3 = EXP2(fmaf(acc[mi][ni][3], EXP_C1, EXP_C2));
            v[mi * 4 + 0] += e0;
            v[mi * 4 + 1] += e1;
            v[mi * 4 + 2] += e2;
            v[mi * 4 + 3] += e3;
            c4[ni] += (e0 + e1) + (e2 + e3);       // tree: SLP-friendly
        }

    // row-sums: multi-value butterfly across mrow, STATIC indices + cndmask.
    // After all stages value r sits on lane mrow==r (R10/R11-verified algebra).
    float r1;
    {
        const bool b8 = (mrow & 8) != 0;
        float r8[8];
#pragma unroll
        for (int k = 0; k < 8; ++k) {
            float own  = b8 ? v[8 + k] : v[k];
            float send = b8 ? v[k]     : v[8 + k];
            r8[k] = own + __shfl_xor(send, 8);
        }
        const bool b4 = (mrow & 4) != 0;
        float r4[4];
#pragma unroll
        for (int k = 0; k < 4; ++k) {
            float own  = b4 ? r8[4 + k] : r8[k];
            float send = b4 ? r8[k]     : r8[4 + k];
            r4[k] = own + __shfl_xor(send, 4);
        }
        const bool b2 = (mrow & 2) != 0;
        float r2[2];
#pragma unroll
        for (int k = 0; k < 2; ++k) {
            float own  = b2 ? r4[2 + k] : r4[k];
            float send = b2 ? r4[k]     : r4[2 + k];
            r2[k] = own + __shfl_xor(send, 2);
        }
        const bool b1 = (mrow & 1) != 0;
        {
            float own  = b1 ? r2[1] : r2[0];
            float send = b1 ? r2[0] : r2[1];
            r1 = own + __shfl_xor(send, 1);
        }
    }
    {
        int row_loc = wm * 64 + (mrow >> 2) * 16 + q * 4 + (mrow & 3);
        partial[(size_t)(rA + row_loc) * 128 + (bx * 2 + wn)] = r1;
    }

    if (offdiag) {
        // col-sums: butterfly across q (xor32 -> bit1, xor16 -> bit0);
        // value ni lands on lanes with q==ni (R10/R11-verified algebra).
        const bool cb1 = (q & 2) != 0;
        float c2[2];
#pragma unroll
        for (int k = 0; k < 2; ++k) {
            float own  = cb1 ? c4[2 + k] : c4[k];
            float send = cb1 ? c4[k]     : c4[2 + k];
            c2[k] = own + __shfl_xor(send, 32);
        }
        const bool cb0 = (q & 1) != 0;
        float c1;
        {
            float own  = cb0 ? c2[1] : c2[0];
            float send = cb0 ? c2[0] : c2[1];
            c1 = own + __shfl_xor(send, 16);
        }
        int col_loc = wn * 64 + q * 16 + mrow;
        partial[(size_t)(rB + col_loc) * 128 + (by * 2 + wm)] = c1;
    }
}

// ---- finalize 1: one wave per pair, deterministic per-block sums ----
__global__ __launch_bounds__(256) void k_finalize1(const float* __restrict__ X,
                                                   const float* __restrict__ partial,
                                                   float* __restrict__ blocksum) {
    __shared__ float ls[4];
    int wave = threadIdx.x >> 6, lane = threadIdx.x & 63;
    int p = blockIdx.x * 4 + wave;
    int i = 2 * p, j = i + 1;

    float pi = partial[(size_t)i * 128 + lane] + partial[(size_t)i * 128 + 64 + lane];
    float pj = partial[(size_t)j * 128 + lane] + partial[(size_t)j * 128 + 64 + lane];
    float xi0 = X[(size_t)i * 128 + lane], xi1 = X[(size_t)i * 128 + 64 + lane];
    float xj0 = X[(size_t)j * 128 + lane], xj1 = X[(size_t)j * 128 + 64 + lane];
    float dii = xi0 * xi0 + xi1 * xi1;
    float dij = xi0 * xj0 + xi1 * xj1;
    float djj = xj0 * xj0 + xj1 * xj1;

#pragma unroll
    for (int m = 1; m < 64; m <<= 1) {
        pi  += __shfl_xor(pi, m);
        pj  += __shfl_xor(pj, m);
        dii += __shfl_xor(dii, m);
        dij += __shfl_xor(dij, m);
        djj += __shfl_xor(djj, m);
    }
    if (lane == 0) {
        dii *= INV_COS; dij *= INV_COS; djj *= INV_COS;
        float eii = EXP2(fmaf(dii, LOG2E, LOG2E));
        float eij = EXP2(fmaf(dij, LOG2E, LOG2E));
        float ejj = EXP2(fmaf(djj, LOG2E, LOG2E));
        float dissim = (pi - eii - eij) + (pj - eij - ejj);
        float J = __logf(1e-8f + dissim) - dij;
        ls[wave] = (J > 0.f) ? J * J : 0.f;
    }
    __syncthreads();
    if (threadIdx.x == 0)
        blocksum[blockIdx.x] = ls[0] + ls[1] + ls[2] + ls[3];
}

// ---- finalize 2: single block reduces 1024 block sums ----
__global__ __launch_bounds__(256) void k_finalize2(const float* __restrict__ blocksum,
                                                   float* __restrict__ out) {
    __shared__ float ls[4];
    int t = threadIdx.x;
    float s = blocksum[t] + blocksum[t + 256] + blocksum[t + 512] + blocksum[t + 768];
#pragma unroll
    for (int m = 1; m < 64; m <<= 1) s += __shfl_xor(s, m);
    if ((t & 63) == 0) ls[t >> 6] = s;
    __syncthreads();
    if (t == 0) out[0] = (ls[0] + ls[1] + ls[2] + ls[3]) * (1.0f / 16384.0f);
}

extern "C" void kernel_launch(void* const* d_in, const int* in_sizes, int n_in,
                              void* d_out, int out_size, void* d_ws, size_t ws_size,
                              hipStream_t stream) {
    const float* X = (const float*)d_in[0];
    char* ws = (char*)d_ws;
    unsigned* X8 = (unsigned*)ws;                        // 1 MiB fp8 input
    float* partial  = (float*)(ws + (1u << 20));         // 4 MiB: partial[8192][128]
    float* blocksum = (float*)(ws + (5u << 20));         // 4 KiB
    float* out      = (float*)d_out;

    hipLaunchKernelGGL(k_convert,     dim3(1024), dim3(256), 0, stream, X, X8);
    hipLaunchKernelGGL(k_gemm_rowsum, dim3(2080), dim3(256), 0, stream, (const unsigned char*)X8, partial);
    hipLaunchKernelGGL(k_finalize1,   dim3(1024), dim3(256), 0, stream, X, partial, blocksum);
    hipLaunchKernelGGL(k_finalize2,   dim3(1),    dim3(256), 0, stream, blocksum, out);
}